// Round 1
// baseline (69.282 us; speedup 1.0000x reference)
//
#include <hip/hip_runtime.h>
#include <math.h>

// Problem constants (match reference setup)
#define NUM_EGO    32
#define AGENTS_PER 128
#define T_TOTAL    34
#define H_OFF      4
#define TN         30           // T_TOTAL - H
#define SCALE      1.9f         // LEAST_MIN_TTC / DT = 0.95 / 0.5

// Single-dispatch design: grid = 32 blocks (one per ego), 768 threads each.
// Threads are 6 groups of 128 (group g = tid>>7 handles timesteps
// t in [5g, 5g+5), agent a = tid&127). Each wave holds a single group, so
// all ego-side loads are wave-uniform (broadcast). Block-internal LDS
// reduction produces out[b] in exactly one deterministic store per ego:
// no init memset node, no cross-block races, one dispatch total.
#define BLOCK  768
#define TPG    5                 // timesteps per group (6*5 = 30 = TN)
#define NWAVES (BLOCK / 64)

__global__ __launch_bounds__(BLOCK) void ttc_fused(
    const float* __restrict__ posg,     // (N, 34, 2)
    const float* __restrict__ headg,    // (N, 34)
    const float* __restrict__ boxg,     // (N, 4)
    const int*   __restrict__ validg,   // (N, 34) 0/1
    const int*   __restrict__ ptrg,     // (33,)
    float* __restrict__ out)            // (32,)
{
    const int b   = blockIdx.x;         // ego index
    const int tid = threadIdx.x;
    const int a   = tid & (AGENTS_PER - 1);   // agent slot 0..127
    const int g   = tid >> 7;                 // timestep group 0..5
    const int e0  = ptrg[b];                  // wave-uniform scalar load
    const int n   = e0 + a;

    // Boxes (loaded once; ego box is a broadcast)
    const float4 ebx = *(const float4*)&boxg[e0 * 4];
    const float4 abx = *(const float4*)&boxg[n * 4];
    const float ef = ebx.x, er = ebx.y, el = ebx.z, ert = ebx.w;
    const float af = abx.x, ar = abx.y, al = abx.z, art = abx.w;

    // local corner offsets (x: front/back, y: left/right)
    const float elx[4] = { ef,  ef, -er, -er };
    const float ely[4] = { el, -ert, -ert,  el };
    const float alx[4] = { af,  af, -ar, -ar };
    const float aly[4] = { al, -art, -art,  al };

    bool anyhit = false;

    const int t0  = g * TPG;
    const int tt0 = t0 + H_OFF;
    // Seed previous positions (pos at tt0-1); each loop iteration reuses the
    // prior iteration's pos[tt] as pos[tt-1] -> one pos load per side per t.
    float2 eprev = *(const float2*)&posg[(e0 * T_TOTAL + tt0 - 1) * 2];
    float2 aprev = *(const float2*)&posg[(n  * T_TOTAL + tt0 - 1) * 2];

    #pragma unroll
    for (int i = 0; i < TPG; ++i) {
        const int tt = tt0 + i;

        const int    ev   = validg[e0 * T_TOTAL + tt];        // broadcast
        const int    av   = validg[n  * T_TOTAL + tt];
        const float2 ecur = *(const float2*)&posg[(e0 * T_TOTAL + tt) * 2];
        const float2 acur = *(const float2*)&posg[(n  * T_TOTAL + tt) * 2];
        const float  eyaw = headg[e0 * T_TOTAL + tt];
        const float  ayaw = headg[n  * T_TOTAL + tt];

        // TTC extrapolated poses
        const float ex = ecur.x + SCALE * (ecur.x - eprev.x);
        const float ey = ecur.y + SCALE * (ecur.y - eprev.y);
        const float ax = acur.x + SCALE * (acur.x - aprev.x);
        const float ay = acur.y + SCALE * (acur.y - aprev.y);
        eprev = ecur; aprev = acur;

        float se, ce, sa, ca;
        __sincosf(eyaw, &se, &ce);
        __sincosf(ayaw, &sa, &ca);

        // L1: ego corners (world) -> agent frame vs agent box
        float L1 = 0.0f;
        #pragma unroll
        for (int k = 0; k < 4; ++k) {
            float cxw = elx[k] * ce - ely[k] * se + ex;
            float cyw = elx[k] * se + ely[k] * ce + ey;
            float dx = cxw - ax;
            float dy = cyw - ay;
            float lx =  dx * ca + dy * sa;
            float ly = -dx * sa + dy * ca;
            float lo = fminf(fmaxf(af - lx, 0.0f), fmaxf(ar + lx, 0.0f));
            float la = fminf(fmaxf(al - ly, 0.0f), fmaxf(art + ly, 0.0f));
            L1 = fmaxf(L1, fminf(lo, la));
        }

        // L2: agent corners (world) -> ego frame vs ego box
        float L2 = 0.0f;
        #pragma unroll
        for (int k = 0; k < 4; ++k) {
            float cxw = alx[k] * ca - aly[k] * sa + ax;
            float cyw = alx[k] * sa + aly[k] * ca + ay;
            float dx = cxw - ex;
            float dy = cyw - ey;
            float lx =  dx * ce + dy * se;
            float ly = -dx * se + dy * ce;
            float lo = fminf(fmaxf(ef - lx, 0.0f), fmaxf(er + lx, 0.0f));
            float la = fminf(fmaxf(el - ly, 0.0f), fmaxf(ert + ly, 0.0f));
            L2 = fmaxf(L2, fminf(lo, la));
        }

        anyhit |= (a != 0) & (ev != 0) & (av != 0) &
                  (fmaxf(L1, L2) > 0.0f);
    }

    // Block reduction: per-wave __any -> LDS -> single deterministic store.
    __shared__ int wflag[NWAVES];
    const int w = tid >> 6;
    const int hitw = __any(anyhit) ? 1 : 0;
    if ((tid & 63) == 0) wflag[w] = hitw;
    __syncthreads();
    if (tid == 0) {
        int f = 0;
        #pragma unroll
        for (int i = 0; i < NWAVES; ++i) f |= wflag[i];
        out[b] = f ? 0.0f : 1.0f;
    }
}

extern "C" void kernel_launch(void* const* d_in, const int* in_sizes, int n_in,
                              void* d_out, int out_size, void* d_ws, size_t ws_size,
                              hipStream_t stream) {
    const float* posg   = (const float*)d_in[0];  // infer_position (N,34,2)
    const float* headg  = (const float*)d_in[1];  // infer_heading  (N,34)
    const float* boxg   = (const float*)d_in[2];  // box            (N,4)
    const int*   validg = (const int*)  d_in[3];  // infer_valid_mask (N,34)
    // d_in[4] = batch (implied by ptr blocks)
    const int*   ptrg   = (const int*)  d_in[5];  // ptr (33,)
    float* out = (float*)d_out;

    // One dispatch, no init node: every out[b] is written exactly once by
    // its block regardless of the harness's zero/poison of d_out.
    ttc_fused<<<NUM_EGO, BLOCK, 0, stream>>>(
        posg, headg, boxg, validg, ptrg, out);
}